// Round 6
// baseline (148.970 us; speedup 1.0000x reference)
//
#include <hip/hip_runtime.h>
#include <cstdint>
#include <cstddef>

#define N_ENT 40000
#define DDIM  128
#define BSZ   1024
#define NJT   313               // ceil(40000/128)
#define NPART (16 * NJT)        // 5008 written partials
#define CH    5                 // j-tiles per block chunk
#define NGRID 1024              // 64 groups x 16 members (group 63 idle)

#define AS1 __attribute__((address_space(1)))
#define AS3 __attribute__((address_space(3)))

typedef short s16x8 __attribute__((ext_vector_type(8)));
typedef float f32x4 __attribute__((ext_vector_type(4)));

// ws layout (bytes), 256-aligned:
//   0       : partials f32[5008]
//   20480   : tpart    f32[1024]
//   24576   : enorm    f32[40000]
//   184576  : cnorm    f32[2048]
//   192768  : c_bf     u16[2048*128]
//   717056  : ent_bf   u16[40000*128]  -> end 10,957,056 B
#define OFF_PART  0
#define OFF_TPART 20480
#define OFF_ENORM 24576
#define OFF_CNORM 184576
#define OFF_CBF   192768
#define OFF_EBF   717056

#define S_CLAMP 15.9423847f      // -ln(2^-23): clip(pred, eps, 1-eps) bound in fp32
#define U_CLAMP 0.159423847f     // S_CLAMP / 100  (s = 100*u)
#define LP_MAX (-1.1920929e-7f)  // ln(fl32(1-1e-7))

__device__ __forceinline__ unsigned short f2bf(float f) {
  uint32_t u = __float_as_uint(f);
  u += 0x7fffu + ((u >> 16) & 1u);   // round-to-nearest-even
  return (unsigned short)(u >> 16);
}

// Skinny prep, float4 width (16 B/lane): unchanged from R15 (verified).
__global__ __launch_bounds__(256) void prep_k(const float* __restrict__ ent,
                                              const int* __restrict__ pos_h,
                                              const int* __restrict__ pos_t,
                                              const int* __restrict__ neg_h,
                                              const float* __restrict__ rpos,
                                              const float* __restrict__ rneg,
                                              const int* __restrict__ l1_flag,
                                              unsigned short* __restrict__ ent_bf,
                                              float* __restrict__ enorm,
                                              unsigned short* __restrict__ c_bf,
                                              float* __restrict__ cnorm,
                                              float* __restrict__ tpart) {
  const int lane = threadIdx.x & 63, wv = threadIdx.x >> 6;
  const int ih = lane >> 5, il = lane & 31;      // half-index, lane-in-half
  const int blk = blockIdx.x;
  if (blk < 5000) {
    int row = blk * 8 + wv * 2 + ih;             // 0..39999
    float4 v = reinterpret_cast<const float4*>(ent + (size_t)row * DDIM)[il];
    ushort4 h4; h4.x = f2bf(v.x); h4.y = f2bf(v.y); h4.z = f2bf(v.z); h4.w = f2bf(v.w);
    reinterpret_cast<ushort4*>(ent_bf + (size_t)row * DDIM)[il] = h4;
    float sq = fmaf(v.x, v.x, fmaf(v.y, v.y, fmaf(v.z, v.z, v.w * v.w)));
    #pragma unroll
    for (int m = 1; m <= 16; m <<= 1) sq += __shfl_xor(sq, m);   // within 32-lane half
    if (il == 0) enorm[row] = sq;
  } else {
    int row = (blk - 5000) * 8 + wv * 2 + ih;    // 0..2047
    int br = row >> 10, i = row & 1023;
    int h = br ? neg_h[i] : pos_h[i];
    const float* rs = br ? rneg : rpos;
    float4 e  = reinterpret_cast<const float4*>(ent + (size_t)h * DDIM)[il];
    float4 rv = reinterpret_cast<const float4*>(rs + (size_t)i * DDIM)[il];
    float c0 = e.x + rv.x, c1 = e.y + rv.y, c2 = e.z + rv.z, c3 = e.w + rv.w;
    ushort4 h4; h4.x = f2bf(c0); h4.y = f2bf(c1); h4.z = f2bf(c2); h4.w = f2bf(c3);
    reinterpret_cast<ushort4*>(c_bf + (size_t)row * DDIM)[il] = h4;
    float sq = fmaf(c0, c0, fmaf(c1, c1, fmaf(c2, c2, c3 * c3)));
    #pragma unroll
    for (int m = 1; m <= 16; m <<= 1) sq += __shfl_xor(sq, m);
    if (il == 0) cnorm[row] = sq;
    if (br == 0) {
      int t = pos_t[i];
      float4 et = reinterpret_cast<const float4*>(ent + (size_t)t * DDIM)[il];
      float d0 = c0 - et.x, d1 = c1 - et.y, d2v = c2 - et.z, d3 = c3 - et.w;
      float d2 = fmaf(d0, d0, fmaf(d1, d1, fmaf(d2v, d2v, d3 * d3)));
      float m1 = fabsf(d0) + fabsf(d1) + fabsf(d2v) + fabsf(d3);
      #pragma unroll
      for (int m = 1; m <= 16; m <<= 1) { d2 += __shfl_xor(d2, m); m1 += __shfl_xor(m1, m); }
      if (il == 0) {
        float s = (*l1_flag) ? (100.f / fmaxf(m1, 1e-12f))
                             : (100.f * rsqrtf(fmaxf(d2, 0.f)));  // d2=0 -> inf, clamps ok
        float x  = __expf(-s);
        float L  = log1pf(x);
        float Bt = fminf(-L, LP_MAX);          // exact log(pred)
        float Ap = fmaxf(-s, -S_CLAMP);        // what main_k adds for this element
        tpart[i] = Bt - Ap;
      }
    }
  }
}

// Main, R17: R16's pipelined persistent-tile structure + 8-WAVE blocks.
// R16 post-mortem: pipeline landed (no spills, 1 barrier/tile) but LDS cap
// (2x32KB dbuf -> 2 blocks/CU) x 4-wave blocks = only 2 waves/SIMD; VALUBusy
// stuck at 50% (dependent-chain stalls exposed), per-tile wall 5.4 µs vs
// ~2.6K cycles of issue work. Lever: waves/SIMD. Block -> 512 threads /
// 8 waves, wave grid 4Mx2N (each wave 32 rows x 64 cols: tm=2, tn=4).
// Per-wave regs shrink (avk[4][2]=32 + acc[2][4]=32 + bv[4]=16 + cnv[8] ->
// ~115 <= 128) so 4 waves/SIMD are allowed; 2 blocks/CU -> 16 waves/CU,
// double R16. B-read pattern (R = wn*64+tn*16+r15, swizzled cs) unchanged ->
// conflict-free as measured; per-thread staging halves (4 chunks of 16B).
// Same per-(jt,mm) math; wave-reduce tree is 8-wide now (absmax may move
// 0 -> ~1e-9, within tolerance). One barrier per tile; STAGE(t+1) issued
// ~full-tile-compute ahead of the barrier that drains it.
__global__ __launch_bounds__(512) void main_k(const unsigned short* __restrict__ c_bf,
                                              const unsigned short* __restrict__ ent_bf,
                                              const float* __restrict__ cnorm,
                                              const float* __restrict__ enorm,
                                              const int* __restrict__ l1_flag,
                                              const int* __restrict__ pos_h,
                                              const int* __restrict__ neg_h,
                                              const float* __restrict__ rpos,
                                              const float* __restrict__ rneg,
                                              const float* __restrict__ ent_f32,
                                              float* __restrict__ partials) {
  __shared__ unsigned short smem[2][128 * 128];   // 64 KB: double-buffered B tile
  __shared__ float s4[2][8];                      // [buffer parity][wave]
  const int id = blockIdx.x;
  const int c8 = id & 7;
  const int q  = id >> 3;
  const int mm = q & 15;                          // member 0..15
  const int gg = q >> 4;                          // 0..7
  const int gp = c8 * 8 + gg;                     // group 0..63
  const int jtB = gp * CH;
  if (jtB >= NJT) return;                         // block-uniform, pre-barrier
  const int nt = (jtB + CH <= NJT) ? CH : (NJT - jtB);
  const int branch = mm & 1;
  const int i0 = (mm >> 1) * 128;
  const int tid = threadIdx.x, lane = tid & 63, wv = tid >> 6;
  const int wm = wv >> 1, wn = wv & 1;            // 4 M-rows x 2 N-cols of waves
  const int r15 = lane & 15, quad = lane >> 4;

  // async stage of one 128x128 B tile into buffer `par`, swizzle c'=c^(row&15)
#define STAGE(par_, j0_) do {                                                  \
    _Pragma("unroll")                                                          \
    for (int i_ = 0; i_ < 4; ++i_) {                                           \
      int g_  = i_ * 512 + tid;     /* LDS dst = uniform base + lane*16 */     \
      int r_  = g_ >> 4;                                                       \
      int c_  = (g_ & 15) ^ (r_ & 15);                                         \
      int jr_ = (j0_) + r_; if (jr_ >= N_ENT) jr_ = N_ENT - 1;                 \
      const unsigned short* src_ = ent_bf + (size_t)jr_ * DDIM + c_ * 8;       \
      __builtin_amdgcn_global_load_lds((const AS1 void*)src_,                  \
          (AS3 void*)(&smem[par_][g_ * 8]), 16, 0, 0);                         \
    }                                                                          \
  } while (0)

  STAGE(0, jtB * 128);                            // tile 0 DMA in flight

  // ---- A fragments -> registers, ALL kc (stay live for the whole block) ----
  const unsigned short* Abase = c_bf + ((size_t)(branch << 10) + i0) * DDIM;
  s16x8 avk[4][2];                                // [kc][tm], 32 VGPRs
  #pragma unroll
  for (int tm = 0; tm < 2; ++tm) {
    const unsigned short* ar = Abase + (size_t)(wm * 32 + tm * 16 + r15) * DDIM + quad * 8;
    #pragma unroll
    for (int kc = 0; kc < 4; ++kc)
      avk[kc][tm] = *reinterpret_cast<const s16x8*>(ar + kc * 32);
  }

  float cnv[8];                                   // fixed for the whole block
  #pragma unroll
  for (int tm = 0; tm < 2; ++tm)
    #pragma unroll
    for (int r = 0; r < 4; ++r)
      cnv[tm * 4 + r] = cnorm[(branch << 10) + i0 + wm * 32 + tm * 16 + quad * 4 + r];

  float en[4];                                    // tile-0 entity norms
  #pragma unroll
  for (int tn = 0; tn < 4; ++tn) {
    int jg = jtB * 128 + wn * 64 + tn * 16 + r15;
    en[tn] = enorm[jg < N_ENT ? jg : N_ENT - 1];
  }

  const int l1 = *l1_flag;
  const f32x4 zf = {0.f, 0.f, 0.f, 0.f};

  __syncthreads();   // drains vmcnt: tile-0 B staged; A/cnv/en landed

  #pragma unroll 1
  for (int t = 0; t < nt; ++t) {
    const int jt  = jtB + t;
    const int j0  = jt * 128;
    const int par = t & 1;
    const bool haveNext = (t + 1) < nt;           // block-uniform

    // issue next tile's DMA NOW — its drain is a full tile-compute away
    if (haveNext) STAGE(par ^ 1, j0 + 128);

    float enx[4];                                 // prefetch next tile's norms
    if (haveNext) {
      #pragma unroll
      for (int tn = 0; tn < 4; ++tn) {
        int jg = j0 + 128 + wn * 64 + tn * 16 + r15;
        enx[tn] = enorm[jg < N_ENT ? jg : N_ENT - 1];
      }
    }

    f32x4 acc[2][4];
    #pragma unroll
    for (int a = 0; a < 2; ++a)
      #pragma unroll
      for (int b = 0; b < 4; ++b) acc[a][b] = zf;

    #pragma unroll
    for (int kc = 0; kc < 4; ++kc) {
      s16x8 bv[4];
      #pragma unroll
      for (int tn = 0; tn < 4; ++tn) {
        int R  = wn * 64 + tn * 16 + r15;
        int cs = (kc * 4 + quad) ^ r15;
        bv[tn] = *reinterpret_cast<const s16x8*>(&smem[par][R * 128 + cs * 8]);
      }
      #pragma unroll
      for (int tm = 0; tm < 2; ++tm)
        #pragma unroll
        for (int tn = 0; tn < 4; ++tn)
          acc[tm][tn] = __builtin_amdgcn_mfma_f32_16x16x32_bf16(avk[kc][tm], bv[tn], acc[tm][tn], 0, 0, 0);
    }

    // ---- epilogue: add, fma, rsqrt, fmin, add (u-units), 4 accumulators ----
    const bool full = (j0 + 128) <= N_ENT;        // block-uniform per tile
    float ls0 = 0.f, ls1 = 0.f, ls2 = 0.f, ls3 = 0.f;
    if (!l1) {
      #pragma unroll
      for (int tm = 0; tm < 2; ++tm) {
        if (full) {
          #pragma unroll
          for (int tn = 0; tn < 4; ++tn) {
            float e0 = en[tn];
            float u0 = rsqrtf(fmaf(-2.f, acc[tm][tn][0], cnv[tm * 4 + 0] + e0));
            float u1 = rsqrtf(fmaf(-2.f, acc[tm][tn][1], cnv[tm * 4 + 1] + e0));
            float u2 = rsqrtf(fmaf(-2.f, acc[tm][tn][2], cnv[tm * 4 + 2] + e0));
            float u3 = rsqrtf(fmaf(-2.f, acc[tm][tn][3], cnv[tm * 4 + 3] + e0));
            ls0 += fminf(u0, U_CLAMP);            // <=0/NaN -> fmin clamps
            ls1 += fminf(u1, U_CLAMP);
            ls2 += fminf(u2, U_CLAMP);
            ls3 += fminf(u3, U_CLAMP);
          }
        } else {
          #pragma unroll
          for (int tn = 0; tn < 4; ++tn) {
            int jg = j0 + wn * 64 + tn * 16 + r15;
            if (jg < N_ENT) {
              float e0 = en[tn];
              ls0 += fminf(rsqrtf(fmaf(-2.f, acc[tm][tn][0], cnv[tm * 4 + 0] + e0)), U_CLAMP);
              ls1 += fminf(rsqrtf(fmaf(-2.f, acc[tm][tn][1], cnv[tm * 4 + 1] + e0)), U_CLAMP);
              ls2 += fminf(rsqrtf(fmaf(-2.f, acc[tm][tn][2], cnv[tm * 4 + 2] + e0)), U_CLAMP);
              ls3 += fminf(rsqrtf(fmaf(-2.f, acc[tm][tn][3], cnv[tm * 4 + 3] + e0)), U_CLAMP);
            }
          }
        }
      }
    } else {
      // L1 fallback (dead with this harness's inputs): recompute on the fly.
      const float* rs = branch ? rneg : rpos;
      const int*   hb = branch ? neg_h : pos_h;
      #pragma unroll 1
      for (int tm = 0; tm < 2; ++tm) {
        #pragma unroll 1
        for (int r = 0; r < 4; ++r) {
          int bi = i0 + wm * 32 + tm * 16 + quad * 4 + r;
          int hh = hb[bi];
          #pragma unroll 1
          for (int tn = 0; tn < 4; ++tn) {
            int jg = j0 + wn * 64 + tn * 16 + r15;
            if (jg < N_ENT) {
              const float* cp1 = ent_f32 + (size_t)hh * DDIM;
              const float* cp2 = rs + (size_t)bi * DDIM;
              const float* ep  = ent_f32 + (size_t)jg * DDIM;
              float man = 0.f;
              #pragma unroll 1
              for (int d = 0; d < DDIM; ++d) man += fabsf(cp1[d] + cp2[d] - ep[d]);
              float s = 100.f / fmaxf(man, 1e-12f);
              ls0 += 0.01f * fminf(s, S_CLAMP);   // same u-unit scale
            }
          }
        }
      }
    }
    float lsum = (ls0 + ls1) + (ls2 + ls3);

    #pragma unroll
    for (int m = 32; m; m >>= 1) lsum += __shfl_xor(lsum, m);
    if (lane == 0) s4[par][wv] = lsum;

    if (haveNext) {                               // rotate prefetched norms
      #pragma unroll
      for (int tn = 0; tn < 4; ++tn) en[tn] = enx[tn];
    }

    __syncthreads();   // drains stage(t+1) — issued a full compute ago; s4 visible
    if (tid == 0) {    // store overlaps next tile's compute; s4[par] safe until t+2
      float a = ((s4[par][0] + s4[par][1]) + (s4[par][2] + s4[par][3]))
              + ((s4[par][4] + s4[par][5]) + (s4[par][6] + s4[par][7]));
      partials[jt * 16 + mm] = a;
    }
  }
#undef STAGE
}

// Single-block deterministic finalize: 1024 threads; each sums ~5 partials
// (x 100/(B*N)) + its tpart element (x -1/(B*N)) in double, block-reduce,
// one plain store. No atomics -> no d_out memset node needed.
__global__ __launch_bounds__(1024) void finalize_k(const float* __restrict__ partials,
                                                   const float* __restrict__ tpart,
                                                   float* __restrict__ out) {
  const int tid = threadIdx.x, lane = tid & 63, wv = tid >> 6;
  const double inv = 1.0 / ((double)BSZ * (double)N_ENT);
  double v = 0.0;
  for (int i = tid; i < NPART; i += 1024) v += (double)partials[i] * (100.0 * inv);
  v += (double)tpart[tid] * (-inv);
  #pragma unroll
  for (int m = 32; m; m >>= 1) v += __shfl_xor(v, m);
  __shared__ double sd[16];
  if (lane == 0) sd[wv] = v;
  __syncthreads();
  if (wv == 0) {
    double t = (lane < 16) ? sd[lane] : 0.0;
    #pragma unroll
    for (int m = 8; m; m >>= 1) t += __shfl_xor(t, m);
    if (lane == 0) out[0] = (float)t;
  }
}

extern "C" void kernel_launch(void* const* d_in, const int* in_sizes, int n_in,
                              void* d_out, int out_size, void* d_ws, size_t ws_size,
                              hipStream_t stream) {
  const int*   pos_h = (const int*)d_in[0];
  const int*   pos_t = (const int*)d_in[1];
  const int*   neg_h = (const int*)d_in[2];
  // d_in[3] = neg_t_batch (unused by reference)
  const float* rpos  = (const float*)d_in[4];
  const float* rneg  = (const float*)d_in[5];
  const float* ent   = (const float*)d_in[6];
  const int*   l1    = (const int*)d_in[7];

  char* ws = (char*)d_ws;
  float*          partials = (float*)(ws + OFF_PART);
  float*          tpart    = (float*)(ws + OFF_TPART);
  float*          enorm    = (float*)(ws + OFF_ENORM);
  float*          cnorm    = (float*)(ws + OFF_CNORM);
  unsigned short* c_bf     = (unsigned short*)(ws + OFF_CBF);
  unsigned short* ent_bf   = (unsigned short*)(ws + OFF_EBF);

  prep_k<<<5256, 256, 0, stream>>>(ent, pos_h, pos_t, neg_h, rpos, rneg, l1,
                                   ent_bf, enorm, c_bf, cnorm, tpart);

  main_k<<<NGRID, 512, 0, stream>>>(c_bf, ent_bf, cnorm, enorm, l1,
                                    pos_h, neg_h, rpos, rneg, ent, partials);

  finalize_k<<<1, 1024, 0, stream>>>(partials, tpart, (float*)d_out);
}

// Round 7
// 143.594 us; speedup vs baseline: 1.0374x; 1.0374x over previous
//
#include <hip/hip_runtime.h>
#include <cstdint>
#include <cstddef>

#define N_ENT 40000
#define DDIM  128
#define BSZ   1024
#define NJT   313               // ceil(40000/128)
#define CH    5                 // j-tiles per block chunk
#define NGRID 1024              // 64 groups x 16 members (group 63 idle)

typedef short s16x8 __attribute__((ext_vector_type(8)));
typedef float f32x4 __attribute__((ext_vector_type(4)));

// ws layout (bytes), 256-aligned (unchanged; partials now only NGRID floats):
//   0       : partials f32[1024]   (per-block sums; idle blocks write 0)
//   20480   : tpart    f32[1024]
//   24576   : enorm    f32[40000]
//   184576  : cnorm    f32[2048]
//   192768  : c_bf     u16[2048*128]
//   717056  : ent_bf   u16[40000*128]  -> end 10,957,056 B
#define OFF_PART  0
#define OFF_TPART 20480
#define OFF_ENORM 24576
#define OFF_CNORM 184576
#define OFF_CBF   192768
#define OFF_EBF   717056

#define S_CLAMP 15.9423847f      // -ln(2^-23): clip(pred, eps, 1-eps) bound in fp32
#define U_CLAMP 0.159423847f     // S_CLAMP / 100  (s = 100*u)
#define LP_MAX (-1.1920929e-7f)  // ln(fl32(1-1e-7))

__device__ __forceinline__ unsigned short f2bf(float f) {
  uint32_t u = __float_as_uint(f);
  u += 0x7fffu + ((u >> 16) & 1u);   // round-to-nearest-even
  return (unsigned short)(u >> 16);
}

// Skinny prep, float4 width (16 B/lane): unchanged from R15 (verified).
__global__ __launch_bounds__(256) void prep_k(const float* __restrict__ ent,
                                              const int* __restrict__ pos_h,
                                              const int* __restrict__ pos_t,
                                              const int* __restrict__ neg_h,
                                              const float* __restrict__ rpos,
                                              const float* __restrict__ rneg,
                                              const int* __restrict__ l1_flag,
                                              unsigned short* __restrict__ ent_bf,
                                              float* __restrict__ enorm,
                                              unsigned short* __restrict__ c_bf,
                                              float* __restrict__ cnorm,
                                              float* __restrict__ tpart) {
  const int lane = threadIdx.x & 63, wv = threadIdx.x >> 6;
  const int ih = lane >> 5, il = lane & 31;      // half-index, lane-in-half
  const int blk = blockIdx.x;
  if (blk < 5000) {
    int row = blk * 8 + wv * 2 + ih;             // 0..39999
    float4 v = reinterpret_cast<const float4*>(ent + (size_t)row * DDIM)[il];
    ushort4 h4; h4.x = f2bf(v.x); h4.y = f2bf(v.y); h4.z = f2bf(v.z); h4.w = f2bf(v.w);
    reinterpret_cast<ushort4*>(ent_bf + (size_t)row * DDIM)[il] = h4;
    float sq = fmaf(v.x, v.x, fmaf(v.y, v.y, fmaf(v.z, v.z, v.w * v.w)));
    #pragma unroll
    for (int m = 1; m <= 16; m <<= 1) sq += __shfl_xor(sq, m);   // within 32-lane half
    if (il == 0) enorm[row] = sq;
  } else {
    int row = (blk - 5000) * 8 + wv * 2 + ih;    // 0..2047
    int br = row >> 10, i = row & 1023;
    int h = br ? neg_h[i] : pos_h[i];
    const float* rs = br ? rneg : rpos;
    float4 e  = reinterpret_cast<const float4*>(ent + (size_t)h * DDIM)[il];
    float4 rv = reinterpret_cast<const float4*>(rs + (size_t)i * DDIM)[il];
    float c0 = e.x + rv.x, c1 = e.y + rv.y, c2 = e.z + rv.z, c3 = e.w + rv.w;
    ushort4 h4; h4.x = f2bf(c0); h4.y = f2bf(c1); h4.z = f2bf(c2); h4.w = f2bf(c3);
    reinterpret_cast<ushort4*>(c_bf + (size_t)row * DDIM)[il] = h4;
    float sq = fmaf(c0, c0, fmaf(c1, c1, fmaf(c2, c2, c3 * c3)));
    #pragma unroll
    for (int m = 1; m <= 16; m <<= 1) sq += __shfl_xor(sq, m);
    if (il == 0) cnorm[row] = sq;
    if (br == 0) {
      int t = pos_t[i];
      float4 et = reinterpret_cast<const float4*>(ent + (size_t)t * DDIM)[il];
      float d0 = c0 - et.x, d1 = c1 - et.y, d2v = c2 - et.z, d3 = c3 - et.w;
      float d2 = fmaf(d0, d0, fmaf(d1, d1, fmaf(d2v, d2v, d3 * d3)));
      float m1 = fabsf(d0) + fabsf(d1) + fabsf(d2v) + fabsf(d3);
      #pragma unroll
      for (int m = 1; m <= 16; m <<= 1) { d2 += __shfl_xor(d2, m); m1 += __shfl_xor(m1, m); }
      if (il == 0) {
        float s = (*l1_flag) ? (100.f / fmaxf(m1, 1e-12f))
                             : (100.f * rsqrtf(fmaxf(d2, 0.f)));  // d2=0 -> inf, clamps ok
        float x  = __expf(-s);
        float L  = log1pf(x);
        float Bt = fminf(-L, LP_MAX);          // exact log(pred)
        float Ap = fmaxf(-s, -S_CLAMP);        // what main_k adds for this element
        tpart[i] = Bt - Ap;
      }
    }
  }
}

// Main, R18: BARRIER-FREE, LDS-FREE streaming. R10..R17 post-mortems: every
// LDS-staged variant sits at ~5 µs/tile vs ~1 µs of pipe work with no pipe
// >52% — the common structure is the per-tile barrier+vmcnt-drain convoy.
// R17 ruled out "just add waves". ent_bf is L2-resident (~1.3 MB/XCD with
// this grouping), so LDS staging only saved 2x L2 traffic; drop it. Each
// wave loads B fragments straight from L2 into registers (16 dwordx4/tile,
// per-kc double-buffered bv0/bv1; next tile's kc0 + norms prefetched under
// the epilogue), A fragments register-resident for the whole 5-tile chunk.
// NO __syncthreads in the tile loop — waves fully async, compiler free to
// pipeline loads across tiles. L2 floor ~9.3 µs (320 MB @ 34.5 TB/s).
// One block = (group gp, member mm); per-block sum accumulated in-wave
// across tiles -> single partial per block (1024 total; idle blocks write
// 0). Same element math as R10 (clamped tail rows masked in epilogue);
// summation regrouping only (well within tolerance). XCD grouping kept:
// all 16 members of a group share id%8 -> one XCD L2 for its 5 B tiles.
__global__ __launch_bounds__(256) void main_k(const unsigned short* __restrict__ c_bf,
                                              const unsigned short* __restrict__ ent_bf,
                                              const float* __restrict__ cnorm,
                                              const float* __restrict__ enorm,
                                              const int* __restrict__ l1_flag,
                                              const int* __restrict__ pos_h,
                                              const int* __restrict__ neg_h,
                                              const float* __restrict__ rpos,
                                              const float* __restrict__ rneg,
                                              const float* __restrict__ ent_f32,
                                              float* __restrict__ partials) {
  __shared__ float s4[4];
  const int id = blockIdx.x;
  const int c8 = id & 7;
  const int q  = id >> 3;
  const int mm = q & 15;                          // member 0..15
  const int gg = q >> 4;                          // 0..7
  const int gp = c8 * 8 + gg;                     // group 0..63
  const int jtB = gp * CH;
  const int tid = threadIdx.x, lane = tid & 63, wv = tid >> 6;
  if (jtB >= NJT) {                               // idle group: zero its partial
    if (tid == 0) partials[id] = 0.f;
    return;
  }
  const int nt = (jtB + CH <= NJT) ? CH : (NJT - jtB);
  const int branch = mm & 1;
  const int i0 = (mm >> 1) * 128;
  const int wm = wv >> 1, wn = wv & 1;            // 2x2 waves, 64x64 each
  const int r15 = lane & 15, quad = lane >> 4;

  // B fragment load: row jg = j0 + wn*64 + tn*16 + r15 (clamped; tail masked
  // in epilogue), 16B at k-chunk (kc*4+quad). 16 rows x 64B per instr, L2-hot.
#define LOADB(dst_, j0_, kc_) do {                                             \
    _Pragma("unroll")                                                          \
    for (int tn_ = 0; tn_ < 4; ++tn_) {                                        \
      int jg_ = (j0_) + wn * 64 + tn_ * 16 + r15;                              \
      if (jg_ >= N_ENT) jg_ = N_ENT - 1;                                       \
      dst_[tn_] = *reinterpret_cast<const s16x8*>(                             \
          ent_bf + (size_t)jg_ * DDIM + ((kc_) * 4 + quad) * 8);               \
    }                                                                          \
  } while (0)

  // ---- A fragments -> registers, ALL kc (live for the whole block) ----
  const unsigned short* Abase = c_bf + ((size_t)(branch << 10) + i0) * DDIM;
  s16x8 avk[4][4];                                // [kc][tm], 64 VGPRs
  #pragma unroll
  for (int tm = 0; tm < 4; ++tm) {
    const unsigned short* ar = Abase + (size_t)(wm * 64 + tm * 16 + r15) * DDIM + quad * 8;
    #pragma unroll
    for (int kc = 0; kc < 4; ++kc)
      avk[kc][tm] = *reinterpret_cast<const s16x8*>(ar + kc * 32);
  }

  float cnv[16];                                  // fixed for the whole block
  #pragma unroll
  for (int tm = 0; tm < 4; ++tm)
    #pragma unroll
    for (int r = 0; r < 4; ++r)
      cnv[tm * 4 + r] = cnorm[(branch << 10) + i0 + wm * 64 + tm * 16 + quad * 4 + r];

  float en[4];                                    // tile-0 entity norms
  #pragma unroll
  for (int tn = 0; tn < 4; ++tn) {
    int jg = jtB * 128 + wn * 64 + tn * 16 + r15;
    en[tn] = enorm[jg < N_ENT ? jg : N_ENT - 1];
  }

  const int l1 = *l1_flag;
  const f32x4 zf = {0.f, 0.f, 0.f, 0.f};

  s16x8 bv0[4], bv1[4];
  LOADB(bv0, jtB * 128, 0);                       // tile-0 kc0 in flight

  float ls0 = 0.f, ls1 = 0.f, ls2 = 0.f, ls3 = 0.f;   // accumulate across tiles

  #pragma unroll 1
  for (int t = 0; t < nt; ++t) {
    const int j0 = (jtB + t) * 128;
    const bool haveNext = (t + 1) < nt;           // block-uniform

    f32x4 acc[4][4];
    #pragma unroll
    for (int a = 0; a < 4; ++a)
      #pragma unroll
      for (int b = 0; b < 4; ++b) acc[a][b] = zf;

    // kc pipeline: load kc+1 while kc computes; bv0/bv1 alternate (static names)
    LOADB(bv1, j0, 1);
    #pragma unroll
    for (int tm = 0; tm < 4; ++tm)
      #pragma unroll
      for (int tn = 0; tn < 4; ++tn)
        acc[tm][tn] = __builtin_amdgcn_mfma_f32_16x16x32_bf16(avk[0][tm], bv0[tn], acc[tm][tn], 0, 0, 0);
    LOADB(bv0, j0, 2);
    #pragma unroll
    for (int tm = 0; tm < 4; ++tm)
      #pragma unroll
      for (int tn = 0; tn < 4; ++tn)
        acc[tm][tn] = __builtin_amdgcn_mfma_f32_16x16x32_bf16(avk[1][tm], bv1[tn], acc[tm][tn], 0, 0, 0);
    LOADB(bv1, j0, 3);
    #pragma unroll
    for (int tm = 0; tm < 4; ++tm)
      #pragma unroll
      for (int tn = 0; tn < 4; ++tn)
        acc[tm][tn] = __builtin_amdgcn_mfma_f32_16x16x32_bf16(avk[2][tm], bv0[tn], acc[tm][tn], 0, 0, 0);
    if (haveNext) LOADB(bv0, j0 + 128, 0);        // next tile kc0 under epilogue
    #pragma unroll
    for (int tm = 0; tm < 4; ++tm)
      #pragma unroll
      for (int tn = 0; tn < 4; ++tn)
        acc[tm][tn] = __builtin_amdgcn_mfma_f32_16x16x32_bf16(avk[3][tm], bv1[tn], acc[tm][tn], 0, 0, 0);

    float enx[4];                                 // next tile norms under epilogue
    if (haveNext) {
      #pragma unroll
      for (int tn = 0; tn < 4; ++tn) {
        int jg = j0 + 128 + wn * 64 + tn * 16 + r15;
        enx[tn] = enorm[jg < N_ENT ? jg : N_ENT - 1];
      }
    }

    // ---- epilogue: add, fma, rsqrt, fmin, add (u-units), 4 accumulators ----
    const bool full = (j0 + 128) <= N_ENT;        // block-uniform per tile
    if (!l1) {
      #pragma unroll
      for (int tm = 0; tm < 4; ++tm) {
        if (full) {
          #pragma unroll
          for (int tn = 0; tn < 4; ++tn) {
            float e0 = en[tn];
            float u0 = rsqrtf(fmaf(-2.f, acc[tm][tn][0], cnv[tm * 4 + 0] + e0));
            float u1 = rsqrtf(fmaf(-2.f, acc[tm][tn][1], cnv[tm * 4 + 1] + e0));
            float u2 = rsqrtf(fmaf(-2.f, acc[tm][tn][2], cnv[tm * 4 + 2] + e0));
            float u3 = rsqrtf(fmaf(-2.f, acc[tm][tn][3], cnv[tm * 4 + 3] + e0));
            ls0 += fminf(u0, U_CLAMP);            // <=0/NaN -> fmin clamps
            ls1 += fminf(u1, U_CLAMP);
            ls2 += fminf(u2, U_CLAMP);
            ls3 += fminf(u3, U_CLAMP);
          }
        } else {
          #pragma unroll
          for (int tn = 0; tn < 4; ++tn) {
            int jg = j0 + wn * 64 + tn * 16 + r15;
            if (jg < N_ENT) {
              float e0 = en[tn];
              ls0 += fminf(rsqrtf(fmaf(-2.f, acc[tm][tn][0], cnv[tm * 4 + 0] + e0)), U_CLAMP);
              ls1 += fminf(rsqrtf(fmaf(-2.f, acc[tm][tn][1], cnv[tm * 4 + 1] + e0)), U_CLAMP);
              ls2 += fminf(rsqrtf(fmaf(-2.f, acc[tm][tn][2], cnv[tm * 4 + 2] + e0)), U_CLAMP);
              ls3 += fminf(rsqrtf(fmaf(-2.f, acc[tm][tn][3], cnv[tm * 4 + 3] + e0)), U_CLAMP);
            }
          }
        }
      }
    } else {
      // L1 fallback (dead with this harness's inputs): recompute on the fly.
      const float* rs = branch ? rneg : rpos;
      const int*   hb = branch ? neg_h : pos_h;
      #pragma unroll 1
      for (int tm = 0; tm < 4; ++tm) {
        #pragma unroll 1
        for (int r = 0; r < 4; ++r) {
          int bi = i0 + wm * 64 + tm * 16 + quad * 4 + r;
          int hh = hb[bi];
          #pragma unroll 1
          for (int tn = 0; tn < 4; ++tn) {
            int jg = j0 + wn * 64 + tn * 16 + r15;
            if (jg < N_ENT) {
              const float* cp1 = ent_f32 + (size_t)hh * DDIM;
              const float* cp2 = rs + (size_t)bi * DDIM;
              const float* ep  = ent_f32 + (size_t)jg * DDIM;
              float man = 0.f;
              #pragma unroll 1
              for (int d = 0; d < DDIM; ++d) man += fabsf(cp1[d] + cp2[d] - ep[d]);
              float s = 100.f / fmaxf(man, 1e-12f);
              ls0 += 0.01f * fminf(s, S_CLAMP);   // same u-unit scale
            }
          }
        }
      }
    }

    if (haveNext) {                               // rotate prefetched norms
      #pragma unroll
      for (int tn = 0; tn < 4; ++tn) en[tn] = enx[tn];
    }
  }

  // one reduction per block (the only barrier in the kernel)
  float lsum = (ls0 + ls1) + (ls2 + ls3);
  #pragma unroll
  for (int m = 32; m; m >>= 1) lsum += __shfl_xor(lsum, m);
  if (lane == 0) s4[wv] = lsum;
  __syncthreads();
  if (tid == 0)
    partials[id] = (s4[0] + s4[1]) + (s4[2] + s4[3]);
#undef LOADB
}

// Single-block deterministic finalize: 1024 threads; thread i takes block-
// partial i (x 100/(B*N)) + tpart[i] (x -1/(B*N)) in double, block-reduce,
// one plain store. No atomics -> no d_out memset node needed.
__global__ __launch_bounds__(1024) void finalize_k(const float* __restrict__ partials,
                                                   const float* __restrict__ tpart,
                                                   float* __restrict__ out) {
  const int tid = threadIdx.x, lane = tid & 63, wv = tid >> 6;
  const double inv = 1.0 / ((double)BSZ * (double)N_ENT);
  double v = (double)partials[tid] * (100.0 * inv) + (double)tpart[tid] * (-inv);
  #pragma unroll
  for (int m = 32; m; m >>= 1) v += __shfl_xor(v, m);
  __shared__ double sd[16];
  if (lane == 0) sd[wv] = v;
  __syncthreads();
  if (wv == 0) {
    double t = (lane < 16) ? sd[lane] : 0.0;
    #pragma unroll
    for (int m = 8; m; m >>= 1) t += __shfl_xor(t, m);
    if (lane == 0) out[0] = (float)t;
  }
}

extern "C" void kernel_launch(void* const* d_in, const int* in_sizes, int n_in,
                              void* d_out, int out_size, void* d_ws, size_t ws_size,
                              hipStream_t stream) {
  const int*   pos_h = (const int*)d_in[0];
  const int*   pos_t = (const int*)d_in[1];
  const int*   neg_h = (const int*)d_in[2];
  // d_in[3] = neg_t_batch (unused by reference)
  const float* rpos  = (const float*)d_in[4];
  const float* rneg  = (const float*)d_in[5];
  const float* ent   = (const float*)d_in[6];
  const int*   l1    = (const int*)d_in[7];

  char* ws = (char*)d_ws;
  float*          partials = (float*)(ws + OFF_PART);
  float*          tpart    = (float*)(ws + OFF_TPART);
  float*          enorm    = (float*)(ws + OFF_ENORM);
  float*          cnorm    = (float*)(ws + OFF_CNORM);
  unsigned short* c_bf     = (unsigned short*)(ws + OFF_CBF);
  unsigned short* ent_bf   = (unsigned short*)(ws + OFF_EBF);

  prep_k<<<5256, 256, 0, stream>>>(ent, pos_h, pos_t, neg_h, rpos, rneg, l1,
                                   ent_bf, enorm, c_bf, cnorm, tpart);

  main_k<<<NGRID, 256, 0, stream>>>(c_bf, ent_bf, cnorm, enorm, l1,
                                    pos_h, neg_h, rpos, rneg, ent, partials);

  finalize_k<<<1, 1024, 0, stream>>>(partials, tpart, (float*)d_out);
}